// Round 1
// baseline (243.898 us; speedup 1.0000x reference)
//
#include <hip/hip_runtime.h>

#define NB 8
#define NT 1024
#define NE 128
#define NH 8
#define NS 16

// Workspace layout (floats). Each of Q/K/V/Y is B*H*T*S = B*T*E = 1048576 floats (4 MB).
#define WS_Q 0
#define WS_K 1048576
#define WS_V 2097152
#define WS_Y 3145728
#define WS_VIDX 4194304

#define WT_PITCH 132  // multiple of 4 -> every row 16B-aligned for float4 LDS reads

static __device__ __forceinline__ void fma4(float4& acc, float s, const float4 v) {
  acc.x = fmaf(s, v.x, acc.x);
  acc.y = fmaf(s, v.y, acc.y);
  acc.z = fmaf(s, v.z, acc.z);
  acc.w = fmaf(s, v.w, acc.w);
}

static __device__ __forceinline__ float dot16(const float4 x0, const float4 x1,
                                              const float4 x2, const float4 x3,
                                              const float4 w0, const float4 w1,
                                              const float4 w2, const float4 w3) {
  float s0 = (x0.x * w0.x + x0.y * w0.y) + (x0.z * w0.z + x0.w * w0.w);
  float s1 = (x1.x * w1.x + x1.y * w1.y) + (x1.z * w1.z + x1.w * w1.w);
  float s2 = (x2.x * w2.x + x2.y * w2.y) + (x2.z * w2.z + x2.w * w2.w);
  float s3 = (x3.x * w3.x + x3.y * w3.y) + (x3.z * w3.z + x3.w * w3.w);
  return (s0 + s1) + (s2 + s3);
}

// ---------------- Kernel A: fused QKV projection + mask compaction -------
// blocks [0,1024): qkv. block -> (h = blk&7, rowgroup = blk>>3 of 64 rows).
// Thread: d = tid&15, rows = base + (tid>>4)*4 .. +3. W rows in registers.
// blocks [1024,1032): per-batch mask compaction (wave 0 only).
__global__ __launch_bounds__(256) void qkv_kernel(
    const float* __restrict__ x, const int* __restrict__ masks,
    const float* __restrict__ Wq, const float* __restrict__ Wk,
    const float* __restrict__ Wv, float* __restrict__ Q, float* __restrict__ K,
    float* __restrict__ V, int* __restrict__ vidx, int* __restrict__ vcount) {
  if (blockIdx.x >= 1024) {
    const int b = blockIdx.x - 1024;
    const int lane = threadIdx.x;
    if (lane < 64) {
      int base = 0;
      for (int c = 0; c < NT; c += 64) {
        int t = c + lane;
        int v = masks[b * NT + t] != 0;
        unsigned long long bal = __ballot(v);
        int pos = base + __popcll(bal & ((1ull << lane) - 1ull));
        if (v) vidx[b * NT + pos] = t;
        base += __popcll(bal);
      }
      if (lane == 0) vcount[b] = base;
    }
    return;
  }
  const int tid = threadIdx.x;
  const int h = blockIdx.x & 7;
  const int rg = blockIdx.x >> 3;  // 0..127
  const int b = rg >> 4;
  const int base = rg << 6;              // global row base (b*NT + t)
  const int d = tid & 15;
  const int r = base + ((tid >> 4) << 2);  // first of this thread's 4 rows
  const float4* wq4 = (const float4*)(Wq + d * 16);
  const float4 wq0 = wq4[0], wq1 = wq4[1], wq2 = wq4[2], wq3 = wq4[3];
  const float4* wk4 = (const float4*)(Wk + d * 16);
  const float4 wk0 = wk4[0], wk1 = wk4[1], wk2 = wk4[2], wk3 = wk4[3];
  const float4* wv4 = (const float4*)(Wv + d * 16);
  const float4 wv0 = wv4[0], wv1 = wv4[1], wv2 = wv4[2], wv3 = wv4[3];
  const float invs = 0.08838834764831845f;  // 1/sqrt(128)
#pragma unroll
  for (int i = 0; i < 4; i++) {
    const int row = r + i;
    const float4* xp = (const float4*)(x + (size_t)row * 128 + h * 16);
    const float4 x0 = xp[0], x1 = xp[1], x2 = xp[2], x3 = xp[3];
    float aq = dot16(x0, x1, x2, x3, wq0, wq1, wq2, wq3);
    float ak = dot16(x0, x1, x2, x3, wk0, wk1, wk2, wk3);
    float av = dot16(x0, x1, x2, x3, wv0, wv1, wv2, wv3);
    const int t = row & 1023;
    size_t o = ((size_t)(b * NH + h) * NT + t) * NS + d;
    Q[o] = aq * invs;
    K[o] = ak;
    V[o] = av;
  }
}

// ---------------- Kernel B: split-K masked attention, 2 queries/thread ---
// grid = B*H*(T/128) = 512 blocks, 512 threads (8 waves = 8 key-splits).
// Block = 128 queries x 8 key-splits. Wave s handles tile rows r == s (mod 8).
// Each thread owns 2 queries (tA = base+lane, tB = tA+64): every K/V LDS read
// feeds 2 dots (preserves the LDS-issue amortization from the 4-split version).
// LDS: Ks/Vs (16 KB) aliased with the 40 KB split-combine buffer `om` (only
// live after the main loop) -> static LDS = 40960 B, 2 blocks/CU = 16 waves/CU
// (vs 8 before): doubles latency hiding, which was the bottleneck
// (VALUBusy 55% @ Occupancy 17%).
__global__ __launch_bounds__(512, 4) void attn_kernel(
    const float* __restrict__ Q, const float* __restrict__ K,
    const float* __restrict__ V, const int* __restrict__ masks,
    const int* __restrict__ vidx, const int* __restrict__ vcount,
    float* __restrict__ Y) {
  // 40960 B shared pool:
  //   main loop:  Ks = smem[0..2047], Vs = smem[2048..4095]   (each [128][16])
  //   epilogue:   om = smem as [8 splits][64 lanes][20]  (o[16], m, l, pad2)
  __shared__ __align__(16) float smem[10240];
  float* Ks = smem;
  float* Vs = smem + 2048;
  const int tid = threadIdx.x;
  const int lane = tid & 63;
  const int split = tid >> 6;  // 0..7
  const int bh = blockIdx.x >> 3;
  const int b = bh >> 3, h = bh & 7;
  const int tbase = (blockIdx.x & 7) << 7;
  const int tA = tbase + lane;
  const int nv = vcount[b];
  const float4* qga = (const float4*)(Q + ((size_t)bh * NT + tA) * NS);
  const float4 qa0 = qga[0], qa1 = qga[1], qa2 = qga[2], qa3 = qga[3];
  const float4* qgb = (const float4*)(Q + ((size_t)bh * NT + tA + 64) * NS);
  const float4 qb0 = qgb[0], qb1 = qgb[1], qb2 = qgb[2], qb3 = qgb[3];
  float mA = -1e30f, lA = 0.f, mB = -1e30f, lB = 0.f;
  float4 oa0 = {0, 0, 0, 0}, oa1 = {0, 0, 0, 0}, oa2 = {0, 0, 0, 0},
         oa3 = {0, 0, 0, 0};
  float4 ob0 = {0, 0, 0, 0}, ob1 = {0, 0, 0, 0}, ob2 = {0, 0, 0, 0},
         ob3 = {0, 0, 0, 0};

  for (int k0 = 0; k0 < nv; k0 += 128) {
    __syncthreads();
    // stage 128 gathered K/V rows cooperatively (zero-fill past nv).
    // 512 threads: one float4 of K and V per thread covers the full tile.
    const int quad = tid & 3;
    const int jr = tid >> 2;  // 0..127
    {
      int j = k0 + jr;
      float4 kv = {0, 0, 0, 0}, vv = {0, 0, 0, 0};
      if (j < nv) {
        int kk = vidx[b * NT + j];
        size_t bse = ((size_t)bh * NT + kk) * NS + (quad << 2);
        kv = *(const float4*)(K + bse);
        vv = *(const float4*)(V + bse);
      }
      *(float4*)(Ks + jr * 16 + (quad << 2)) = kv;
      *(float4*)(Vs + jr * 16 + (quad << 2)) = vv;
    }
    __syncthreads();
    int jmax = nv - k0;
    if (jmax > 128) jmax = 128;
    for (int g = 0; g < 4; g++) {
      const int rbase = split + (g << 5);
      if (rbase >= jmax) break;  // wave-uniform
      float sA[4], sB[4];
#pragma unroll
      for (int i = 0; i < 4; i++) {
        const float4* kr = (const float4*)(Ks + (rbase + (i << 3)) * 16);
        float4 k0v = kr[0], k1v = kr[1], k2v = kr[2], k3v = kr[3];
        sA[i] = dot16(qa0, qa1, qa2, qa3, k0v, k1v, k2v, k3v);
        sB[i] = dot16(qb0, qb1, qb2, qb3, k0v, k1v, k2v, k3v);
      }
#pragma unroll
      for (int i = 0; i < 4; i++)
        if (rbase + (i << 3) >= jmax) { sA[i] = -1e30f; sB[i] = -1e30f; }
      // online update, query A
      float mbA = fmaxf(fmaxf(sA[0], sA[1]), fmaxf(sA[2], sA[3]));
      if (mbA > mA) {
        float al = __expf(mA - mbA);
        lA *= al;
        oa0.x *= al; oa0.y *= al; oa0.z *= al; oa0.w *= al;
        oa1.x *= al; oa1.y *= al; oa1.z *= al; oa1.w *= al;
        oa2.x *= al; oa2.y *= al; oa2.z *= al; oa2.w *= al;
        oa3.x *= al; oa3.y *= al; oa3.z *= al; oa3.w *= al;
        mA = mbA;
      }
      float pA[4];
      pA[0] = __expf(sA[0] - mA); pA[1] = __expf(sA[1] - mA);
      pA[2] = __expf(sA[2] - mA); pA[3] = __expf(sA[3] - mA);
      lA += (pA[0] + pA[1]) + (pA[2] + pA[3]);
      // online update, query B
      float mbB = fmaxf(fmaxf(sB[0], sB[1]), fmaxf(sB[2], sB[3]));
      if (mbB > mB) {
        float al = __expf(mB - mbB);
        lB *= al;
        ob0.x *= al; ob0.y *= al; ob0.z *= al; ob0.w *= al;
        ob1.x *= al; ob1.y *= al; ob1.z *= al; ob1.w *= al;
        ob2.x *= al; ob2.y *= al; ob2.z *= al; ob2.w *= al;
        ob3.x *= al; ob3.y *= al; ob3.z *= al; ob3.w *= al;
        mB = mbB;
      }
      float pB[4];
      pB[0] = __expf(sB[0] - mB); pB[1] = __expf(sB[1] - mB);
      pB[2] = __expf(sB[2] - mB); pB[3] = __expf(sB[3] - mB);
      lB += (pB[0] + pB[1]) + (pB[2] + pB[3]);
#pragma unroll
      for (int i = 0; i < 4; i++) {
        const float4* vr = (const float4*)(Vs + (rbase + (i << 3)) * 16);
        float4 v0 = vr[0], v1 = vr[1], v2 = vr[2], v3 = vr[3];
        fma4(oa0, pA[i], v0); fma4(oa1, pA[i], v1);
        fma4(oa2, pA[i], v2); fma4(oa3, pA[i], v3);
        fma4(ob0, pB[i], v0); fma4(ob1, pB[i], v1);
        fma4(ob2, pB[i], v2); fma4(ob3, pB[i], v3);
      }
    }
  }
  // ---- two-phase epilogue: om aliases Ks/Vs, so sync before overwriting ----
  __syncthreads();
  float* om = smem;  // [8][64][20]
  // phase 1: query-group A (queries tbase + 0..63)
  {
    float* pa = om + (split * 64 + lane) * 20;
    *(float4*)(pa + 0) = oa0; *(float4*)(pa + 4) = oa1;
    *(float4*)(pa + 8) = oa2; *(float4*)(pa + 12) = oa3;
    pa[16] = mA; pa[17] = lA;
  }
  __syncthreads();
  if (tid < 64) {
    const int tq = tbase + tid;
    float ms[8], ls[8];
#pragma unroll
    for (int s = 0; s < 8; s++) {
      const float* p = om + (s * 64 + tid) * 20;
      ms[s] = p[16]; ls[s] = p[17];
    }
    float M = fmaxf(fmaxf(fmaxf(ms[0], ms[1]), fmaxf(ms[2], ms[3])),
                    fmaxf(fmaxf(ms[4], ms[5]), fmaxf(ms[6], ms[7])));
    float L = 0.f;
    float4 y0 = {0, 0, 0, 0}, y1 = {0, 0, 0, 0}, y2 = {0, 0, 0, 0},
           y3 = {0, 0, 0, 0};
#pragma unroll
    for (int s = 0; s < 8; s++) {
      float f = __expf(ms[s] - M);
      L = fmaf(f, ls[s], L);
      const float* p = om + (s * 64 + tid) * 20;
      fma4(y0, f, *(const float4*)(p + 0));
      fma4(y1, f, *(const float4*)(p + 4));
      fma4(y2, f, *(const float4*)(p + 8));
      fma4(y3, f, *(const float4*)(p + 12));
    }
    const int qm = masks[b * NT + tq];
    const float inv = (qm != 0 && L > 0.f) ? (1.0f / L) : 0.f;
    y0.x *= inv; y0.y *= inv; y0.z *= inv; y0.w *= inv;
    y1.x *= inv; y1.y *= inv; y1.z *= inv; y1.w *= inv;
    y2.x *= inv; y2.y *= inv; y2.z *= inv; y2.w *= inv;
    y3.x *= inv; y3.y *= inv; y3.z *= inv; y3.w *= inv;
    float4* yo = (float4*)(Y + ((size_t)b * NT + tq) * NE + h * NS);
    yo[0] = y0; yo[1] = y1; yo[2] = y2; yo[3] = y3;
  }
  __syncthreads();
  // phase 2: query-group B (queries tbase + 64..127)
  {
    float* pb = om + (split * 64 + lane) * 20;
    *(float4*)(pb + 0) = ob0; *(float4*)(pb + 4) = ob1;
    *(float4*)(pb + 8) = ob2; *(float4*)(pb + 12) = ob3;
    pb[16] = mB; pb[17] = lB;
  }
  __syncthreads();
  if (tid < 64) {
    const int tq = tbase + 64 + tid;
    float ms[8], ls[8];
#pragma unroll
    for (int s = 0; s < 8; s++) {
      const float* p = om + (s * 64 + tid) * 20;
      ms[s] = p[16]; ls[s] = p[17];
    }
    float M = fmaxf(fmaxf(fmaxf(ms[0], ms[1]), fmaxf(ms[2], ms[3])),
                    fmaxf(fmaxf(ms[4], ms[5]), fmaxf(ms[6], ms[7])));
    float L = 0.f;
    float4 y0 = {0, 0, 0, 0}, y1 = {0, 0, 0, 0}, y2 = {0, 0, 0, 0},
           y3 = {0, 0, 0, 0};
#pragma unroll
    for (int s = 0; s < 8; s++) {
      float f = __expf(ms[s] - M);
      L = fmaf(f, ls[s], L);
      const float* p = om + (s * 64 + tid) * 20;
      fma4(y0, f, *(const float4*)(p + 0));
      fma4(y1, f, *(const float4*)(p + 4));
      fma4(y2, f, *(const float4*)(p + 8));
      fma4(y3, f, *(const float4*)(p + 12));
    }
    const int qm = masks[b * NT + tq];
    const float inv = (qm != 0 && L > 0.f) ? (1.0f / L) : 0.f;
    y0.x *= inv; y0.y *= inv; y0.z *= inv; y0.w *= inv;
    y1.x *= inv; y1.y *= inv; y1.z *= inv; y1.w *= inv;
    y2.x *= inv; y2.y *= inv; y2.z *= inv; y2.w *= inv;
    y3.x *= inv; y3.y *= inv; y3.z *= inv; y3.w *= inv;
    float4* yo = (float4*)(Y + ((size_t)b * NT + tq) * NE + h * NS);
    yo[0] = y0; yo[1] = y1; yo[2] = y2; yo[3] = y3;
  }
}

// ---------------- Kernel C: out = Y @ Wu^T + bu --------------------------
// grid = B*T/16 = 512 blocks (2 blocks/CU), 256 threads.
// 16 rows/block; threads: c0 = 4 cols, rg = 4 rowgroups x 4 rows, eh = e-half.
// 2-way e-split within block; partials combined via LDS (Wt reused).
__global__ __launch_bounds__(256) void proj_kernel(
    const float* __restrict__ Y, const float* __restrict__ Wu,
    const float* __restrict__ bu, float* __restrict__ out) {
  __shared__ __align__(16) float Wt[64 * WT_PITCH];  // 33792 B
  __shared__ __align__(16) float Yt[16 * 128];       // 8192 B
  const int tid = threadIdx.x;
  const int r0 = blockIdx.x * 16;
  const float4* yg = (const float4*)(Y + (size_t)r0 * 128);
  float4* yt4 = (float4*)Yt;
  yt4[tid] = yg[tid];
  yt4[tid + 256] = yg[tid + 256];
  const int c0 = (tid & 31) << 2;
  const int rg = (tid >> 5) & 3;
  const int eh = tid >> 7;  // 0 or 1
  float4 acc0 = {0, 0, 0, 0}, acc1 = {0, 0, 0, 0}, acc2 = {0, 0, 0, 0},
         acc3 = {0, 0, 0, 0};
  for (int e0 = 0; e0 < 128; e0 += 64) {
    __syncthreads();  // guards Yt staging (iter 0) and Wt reuse (iter 1)
#pragma unroll
    for (int p = 0; p < 8; p++) {
      int idx = tid + p * 256;
      int c = idx >> 4;
      int es = (idx & 15) << 2;
      float4 w = *(const float4*)(Wu + c * 128 + e0 + es);
      Wt[(es + 0) * WT_PITCH + c] = w.x;
      Wt[(es + 1) * WT_PITCH + c] = w.y;
      Wt[(es + 2) * WT_PITCH + c] = w.z;
      Wt[(es + 3) * WT_PITCH + c] = w.w;
    }
    __syncthreads();
    const int eb = eh << 5;  // this thread's e-half within the 64-chunk
    const float* y0 = Yt + (rg * 4 + 0) * 128 + e0 + eb;
    const float* y1 = Yt + (rg * 4 + 1) * 128 + e0 + eb;
    const float* y2 = Yt + (rg * 4 + 2) * 128 + e0 + eb;
    const float* y3 = Yt + (rg * 4 + 3) * 128 + e0 + eb;
#pragma unroll 4
    for (int e = 0; e < 32; e += 4) {
      const float* wb = Wt + (eb + e) * WT_PITCH + c0;
      float4 w0 = *(const float4*)(wb + 0 * WT_PITCH);
      float4 w1 = *(const float4*)(wb + 1 * WT_PITCH);
      float4 w2 = *(const float4*)(wb + 2 * WT_PITCH);
      float4 w3 = *(const float4*)(wb + 3 * WT_PITCH);
      float4 ya = *(const float4*)(y0 + e);
      float4 yb = *(const float4*)(y1 + e);
      float4 yc = *(const float4*)(y2 + e);
      float4 yd = *(const float4*)(y3 + e);
      fma4(acc0, ya.x, w0); fma4(acc0, ya.y, w1); fma4(acc0, ya.z, w2); fma4(acc0, ya.w, w3);
      fma4(acc1, yb.x, w0); fma4(acc1, yb.y, w1); fma4(acc1, yb.z, w2); fma4(acc1, yb.w, w3);
      fma4(acc2, yc.x, w0); fma4(acc2, yc.y, w1); fma4(acc2, yc.z, w2); fma4(acc2, yc.w, w3);
      fma4(acc3, yd.x, w0); fma4(acc3, yd.y, w1); fma4(acc3, yd.z, w2); fma4(acc3, yd.w, w3);
    }
  }
  // combine e-halves through LDS (Wt dead; pitch 20 to spread banks)
  __syncthreads();
  if (eh == 1) {
    float* p = Wt + (tid & 127) * 20;
    *(float4*)(p + 0) = acc0; *(float4*)(p + 4) = acc1;
    *(float4*)(p + 8) = acc2; *(float4*)(p + 12) = acc3;
  }
  __syncthreads();
  if (eh == 0) {
    const float* p = Wt + tid * 20;
    float4 b4 = *(const float4*)(bu + c0);
    float4 q0 = *(const float4*)(p + 0);
    float4 q1 = *(const float4*)(p + 4);
    float4 q2 = *(const float4*)(p + 8);
    float4 q3 = *(const float4*)(p + 12);
    acc0.x += q0.x + b4.x; acc0.y += q0.y + b4.y; acc0.z += q0.z + b4.z; acc0.w += q0.w + b4.w;
    acc1.x += q1.x + b4.x; acc1.y += q1.y + b4.y; acc1.z += q1.z + b4.z; acc1.w += q1.w + b4.w;
    acc2.x += q2.x + b4.x; acc2.y += q2.y + b4.y; acc2.z += q2.z + b4.z; acc2.w += q2.w + b4.w;
    acc3.x += q3.x + b4.x; acc3.y += q3.y + b4.y; acc3.z += q3.z + b4.z; acc3.w += q3.w + b4.w;
    *(float4*)(out + (size_t)(r0 + rg * 4 + 0) * 128 + c0) = acc0;
    *(float4*)(out + (size_t)(r0 + rg * 4 + 1) * 128 + c0) = acc1;
    *(float4*)(out + (size_t)(r0 + rg * 4 + 2) * 128 + c0) = acc2;
    *(float4*)(out + (size_t)(r0 + rg * 4 + 3) * 128 + c0) = acc3;
  }
}

extern "C" void kernel_launch(void* const* d_in, const int* in_sizes, int n_in,
                              void* d_out, int out_size, void* d_ws,
                              size_t ws_size, hipStream_t stream) {
  const float* x = (const float*)d_in[0];
  const int* masks = (const int*)d_in[1];
  const float* Wq = (const float*)d_in[2];
  const float* Wk = (const float*)d_in[3];
  const float* Wv = (const float*)d_in[4];
  const float* Wu = (const float*)d_in[5];
  const float* bu = (const float*)d_in[6];
  float* out = (float*)d_out;

  float* ws = (float*)d_ws;
  float* Q = ws + WS_Q;
  float* K = ws + WS_K;
  float* V = ws + WS_V;
  float* Y = ws + WS_Y;
  int* vidx = (int*)(ws + WS_VIDX);
  int* vcount = vidx + NB * NT;

  qkv_kernel<<<1024 + NB, 256, 0, stream>>>(x, masks, Wq, Wk, Wv, Q, K, V,
                                            vidx, vcount);
  attn_kernel<<<NB * NH * (NT / 128), 512, 0, stream>>>(Q, K, V, masks, vidx,
                                                        vcount, Y);
  proj_kernel<<<NB * NT / 16, 256, 0, stream>>>(Y, Wu, bu, out);
}

// Round 2
// 147.635 us; speedup vs baseline: 1.6520x; 1.6520x over previous
//
#include <hip/hip_runtime.h>

#define NB 8
#define NT 1024
#define NE 128
#define NH 8
#define NS 16

// Workspace layout (floats). Each of Q/K/V/Y is B*H*T*S = B*T*E = 1048576 floats (4 MB).
#define WS_Q 0
#define WS_K 1048576
#define WS_V 2097152
#define WS_Y 3145728
#define WS_VIDX 4194304

#define WT_PITCH 132  // multiple of 4 -> every row 16B-aligned for float4 LDS reads

static __device__ __forceinline__ void fma4(float4& acc, float s, const float4 v) {
  acc.x = fmaf(s, v.x, acc.x);
  acc.y = fmaf(s, v.y, acc.y);
  acc.z = fmaf(s, v.z, acc.z);
  acc.w = fmaf(s, v.w, acc.w);
}

static __device__ __forceinline__ float dot16(const float4 x0, const float4 x1,
                                              const float4 x2, const float4 x3,
                                              const float4 w0, const float4 w1,
                                              const float4 w2, const float4 w3) {
  float s0 = (x0.x * w0.x + x0.y * w0.y) + (x0.z * w0.z + x0.w * w0.w);
  float s1 = (x1.x * w1.x + x1.y * w1.y) + (x1.z * w1.z + x1.w * w1.w);
  float s2 = (x2.x * w2.x + x2.y * w2.y) + (x2.z * w2.z + x2.w * w2.w);
  float s3 = (x3.x * w3.x + x3.y * w3.y) + (x3.z * w3.z + x3.w * w3.w);
  return (s0 + s1) + (s2 + s3);
}

// ---------------- Kernel A: fused QKV projection + mask compaction -------
// blocks [0,1024): qkv. block -> (h = blk&7, rowgroup = blk>>3 of 64 rows).
// Thread: d = tid&15, rows = base + (tid>>4)*4 .. +3. W rows in registers.
// blocks [1024,1032): per-batch mask compaction (wave 0 only).
__global__ __launch_bounds__(256) void qkv_kernel(
    const float* __restrict__ x, const int* __restrict__ masks,
    const float* __restrict__ Wq, const float* __restrict__ Wk,
    const float* __restrict__ Wv, float* __restrict__ Q, float* __restrict__ K,
    float* __restrict__ V, int* __restrict__ vidx, int* __restrict__ vcount) {
  if (blockIdx.x >= 1024) {
    const int b = blockIdx.x - 1024;
    const int lane = threadIdx.x;
    if (lane < 64) {
      int base = 0;
      for (int c = 0; c < NT; c += 64) {
        int t = c + lane;
        int v = masks[b * NT + t] != 0;
        unsigned long long bal = __ballot(v);
        int pos = base + __popcll(bal & ((1ull << lane) - 1ull));
        if (v) vidx[b * NT + pos] = t;
        base += __popcll(bal);
      }
      if (lane == 0) vcount[b] = base;
    }
    return;
  }
  const int tid = threadIdx.x;
  const int h = blockIdx.x & 7;
  const int rg = blockIdx.x >> 3;  // 0..127
  const int b = rg >> 4;
  const int base = rg << 6;              // global row base (b*NT + t)
  const int d = tid & 15;
  const int r = base + ((tid >> 4) << 2);  // first of this thread's 4 rows
  const float4* wq4 = (const float4*)(Wq + d * 16);
  const float4 wq0 = wq4[0], wq1 = wq4[1], wq2 = wq4[2], wq3 = wq4[3];
  const float4* wk4 = (const float4*)(Wk + d * 16);
  const float4 wk0 = wk4[0], wk1 = wk4[1], wk2 = wk4[2], wk3 = wk4[3];
  const float4* wv4 = (const float4*)(Wv + d * 16);
  const float4 wv0 = wv4[0], wv1 = wv4[1], wv2 = wv4[2], wv3 = wv4[3];
  const float invs = 0.08838834764831845f;  // 1/sqrt(128)
#pragma unroll
  for (int i = 0; i < 4; i++) {
    const int row = r + i;
    const float4* xp = (const float4*)(x + (size_t)row * 128 + h * 16);
    const float4 x0 = xp[0], x1 = xp[1], x2 = xp[2], x3 = xp[3];
    float aq = dot16(x0, x1, x2, x3, wq0, wq1, wq2, wq3);
    float ak = dot16(x0, x1, x2, x3, wk0, wk1, wk2, wk3);
    float av = dot16(x0, x1, x2, x3, wv0, wv1, wv2, wv3);
    const int t = row & 1023;
    size_t o = ((size_t)(b * NH + h) * NT + t) * NS + d;
    Q[o] = aq * invs;
    K[o] = ak;
    V[o] = av;
  }
}

// ---------------- Kernel B: split-K masked attention, 2 queries/thread ---
// grid = B*H*(T/128) = 512 blocks, 512 threads (8 waves = 8 key-splits).
// Block = 128 queries x 8 key-splits. Wave s handles tile rows r == s (mod 8).
// Each thread owns 2 queries (tA = base+lane, tB = tA+64): every K/V LDS read
// feeds 2 dots (preserves the LDS-issue amortization from the 4-split version).
// LDS: Ks/Vs (16 KB) aliased with the 40 KB split-combine buffer `om` (only
// live after the main loop) -> static LDS = 40960 B, 2 blocks/CU = 16 waves/CU.
// NOTE round-1 post-mortem: __launch_bounds__(512, 4) capped VGPR at 64 ->
// ~90 live regs spilled to scratch -> WRITE_SIZE 491 MB, 163 us. Plain
// __launch_bounds__(512) lets the allocator keep all state in registers
// (~96 VGPR); 2 blocks/CU (8 waves each) = 4 waves/SIMD, same occupancy
// target without the spill.
__global__ __launch_bounds__(512) void attn_kernel(
    const float* __restrict__ Q, const float* __restrict__ K,
    const float* __restrict__ V, const int* __restrict__ masks,
    const int* __restrict__ vidx, const int* __restrict__ vcount,
    float* __restrict__ Y) {
  // 40960 B shared pool:
  //   main loop:  Ks = smem[0..2047], Vs = smem[2048..4095]   (each [128][16])
  //   epilogue:   om = smem as [8 splits][64 lanes][20]  (o[16], m, l, pad2)
  __shared__ __align__(16) float smem[10240];
  float* Ks = smem;
  float* Vs = smem + 2048;
  const int tid = threadIdx.x;
  const int lane = tid & 63;
  const int split = tid >> 6;  // 0..7
  const int bh = blockIdx.x >> 3;
  const int b = bh >> 3, h = bh & 7;
  const int tbase = (blockIdx.x & 7) << 7;
  const int tA = tbase + lane;
  const int nv = vcount[b];
  const float4* qga = (const float4*)(Q + ((size_t)bh * NT + tA) * NS);
  const float4 qa0 = qga[0], qa1 = qga[1], qa2 = qga[2], qa3 = qga[3];
  const float4* qgb = (const float4*)(Q + ((size_t)bh * NT + tA + 64) * NS);
  const float4 qb0 = qgb[0], qb1 = qgb[1], qb2 = qgb[2], qb3 = qgb[3];
  float mA = -1e30f, lA = 0.f, mB = -1e30f, lB = 0.f;
  float4 oa0 = {0, 0, 0, 0}, oa1 = {0, 0, 0, 0}, oa2 = {0, 0, 0, 0},
         oa3 = {0, 0, 0, 0};
  float4 ob0 = {0, 0, 0, 0}, ob1 = {0, 0, 0, 0}, ob2 = {0, 0, 0, 0},
         ob3 = {0, 0, 0, 0};

  for (int k0 = 0; k0 < nv; k0 += 128) {
    __syncthreads();
    // stage 128 gathered K/V rows cooperatively (zero-fill past nv).
    // 512 threads: one float4 of K and V per thread covers the full tile.
    const int quad = tid & 3;
    const int jr = tid >> 2;  // 0..127
    {
      int j = k0 + jr;
      float4 kv = {0, 0, 0, 0}, vv = {0, 0, 0, 0};
      if (j < nv) {
        int kk = vidx[b * NT + j];
        size_t bse = ((size_t)bh * NT + kk) * NS + (quad << 2);
        kv = *(const float4*)(K + bse);
        vv = *(const float4*)(V + bse);
      }
      *(float4*)(Ks + jr * 16 + (quad << 2)) = kv;
      *(float4*)(Vs + jr * 16 + (quad << 2)) = vv;
    }
    __syncthreads();
    int jmax = nv - k0;
    if (jmax > 128) jmax = 128;
    for (int g = 0; g < 4; g++) {
      const int rbase = split + (g << 5);
      if (rbase >= jmax) break;  // wave-uniform
      float sA[4], sB[4];
#pragma unroll
      for (int i = 0; i < 4; i++) {
        const float4* kr = (const float4*)(Ks + (rbase + (i << 3)) * 16);
        float4 k0v = kr[0], k1v = kr[1], k2v = kr[2], k3v = kr[3];
        sA[i] = dot16(qa0, qa1, qa2, qa3, k0v, k1v, k2v, k3v);
        sB[i] = dot16(qb0, qb1, qb2, qb3, k0v, k1v, k2v, k3v);
      }
#pragma unroll
      for (int i = 0; i < 4; i++)
        if (rbase + (i << 3) >= jmax) { sA[i] = -1e30f; sB[i] = -1e30f; }
      // online update, query A
      float mbA = fmaxf(fmaxf(sA[0], sA[1]), fmaxf(sA[2], sA[3]));
      if (mbA > mA) {
        float al = __expf(mA - mbA);
        lA *= al;
        oa0.x *= al; oa0.y *= al; oa0.z *= al; oa0.w *= al;
        oa1.x *= al; oa1.y *= al; oa1.z *= al; oa1.w *= al;
        oa2.x *= al; oa2.y *= al; oa2.z *= al; oa2.w *= al;
        oa3.x *= al; oa3.y *= al; oa3.z *= al; oa3.w *= al;
        mA = mbA;
      }
      float pA[4];
      pA[0] = __expf(sA[0] - mA); pA[1] = __expf(sA[1] - mA);
      pA[2] = __expf(sA[2] - mA); pA[3] = __expf(sA[3] - mA);
      lA += (pA[0] + pA[1]) + (pA[2] + pA[3]);
      // online update, query B
      float mbB = fmaxf(fmaxf(sB[0], sB[1]), fmaxf(sB[2], sB[3]));
      if (mbB > mB) {
        float al = __expf(mB - mbB);
        lB *= al;
        ob0.x *= al; ob0.y *= al; ob0.z *= al; ob0.w *= al;
        ob1.x *= al; ob1.y *= al; ob1.z *= al; ob1.w *= al;
        ob2.x *= al; ob2.y *= al; ob2.z *= al; ob2.w *= al;
        ob3.x *= al; ob3.y *= al; ob3.z *= al; ob3.w *= al;
        mB = mbB;
      }
      float pB[4];
      pB[0] = __expf(sB[0] - mB); pB[1] = __expf(sB[1] - mB);
      pB[2] = __expf(sB[2] - mB); pB[3] = __expf(sB[3] - mB);
      lB += (pB[0] + pB[1]) + (pB[2] + pB[3]);
#pragma unroll
      for (int i = 0; i < 4; i++) {
        const float4* vr = (const float4*)(Vs + (rbase + (i << 3)) * 16);
        float4 v0 = vr[0], v1 = vr[1], v2 = vr[2], v3 = vr[3];
        fma4(oa0, pA[i], v0); fma4(oa1, pA[i], v1);
        fma4(oa2, pA[i], v2); fma4(oa3, pA[i], v3);
        fma4(ob0, pB[i], v0); fma4(ob1, pB[i], v1);
        fma4(ob2, pB[i], v2); fma4(ob3, pB[i], v3);
      }
    }
  }
  // ---- two-phase epilogue: om aliases Ks/Vs, so sync before overwriting ----
  __syncthreads();
  float* om = smem;  // [8][64][20]
  // phase 1: query-group A (queries tbase + 0..63)
  {
    float* pa = om + (split * 64 + lane) * 20;
    *(float4*)(pa + 0) = oa0; *(float4*)(pa + 4) = oa1;
    *(float4*)(pa + 8) = oa2; *(float4*)(pa + 12) = oa3;
    pa[16] = mA; pa[17] = lA;
  }
  __syncthreads();
  if (tid < 64) {
    const int tq = tbase + tid;
    float ms[8], ls[8];
#pragma unroll
    for (int s = 0; s < 8; s++) {
      const float* p = om + (s * 64 + tid) * 20;
      ms[s] = p[16]; ls[s] = p[17];
    }
    float M = fmaxf(fmaxf(fmaxf(ms[0], ms[1]), fmaxf(ms[2], ms[3])),
                    fmaxf(fmaxf(ms[4], ms[5]), fmaxf(ms[6], ms[7])));
    float L = 0.f;
    float4 y0 = {0, 0, 0, 0}, y1 = {0, 0, 0, 0}, y2 = {0, 0, 0, 0},
           y3 = {0, 0, 0, 0};
#pragma unroll
    for (int s = 0; s < 8; s++) {
      float f = __expf(ms[s] - M);
      L = fmaf(f, ls[s], L);
      const float* p = om + (s * 64 + tid) * 20;
      fma4(y0, f, *(const float4*)(p + 0));
      fma4(y1, f, *(const float4*)(p + 4));
      fma4(y2, f, *(const float4*)(p + 8));
      fma4(y3, f, *(const float4*)(p + 12));
    }
    const int qm = masks[b * NT + tq];
    const float inv = (qm != 0 && L > 0.f) ? (1.0f / L) : 0.f;
    y0.x *= inv; y0.y *= inv; y0.z *= inv; y0.w *= inv;
    y1.x *= inv; y1.y *= inv; y1.z *= inv; y1.w *= inv;
    y2.x *= inv; y2.y *= inv; y2.z *= inv; y2.w *= inv;
    y3.x *= inv; y3.y *= inv; y3.z *= inv; y3.w *= inv;
    float4* yo = (float4*)(Y + ((size_t)b * NT + tq) * NE + h * NS);
    yo[0] = y0; yo[1] = y1; yo[2] = y2; yo[3] = y3;
  }
  __syncthreads();
  // phase 2: query-group B (queries tbase + 64..127)
  {
    float* pb = om + (split * 64 + lane) * 20;
    *(float4*)(pb + 0) = ob0; *(float4*)(pb + 4) = ob1;
    *(float4*)(pb + 8) = ob2; *(float4*)(pb + 12) = ob3;
    pb[16] = mB; pb[17] = lB;
  }
  __syncthreads();
  if (tid < 64) {
    const int tq = tbase + 64 + tid;
    float ms[8], ls[8];
#pragma unroll
    for (int s = 0; s < 8; s++) {
      const float* p = om + (s * 64 + tid) * 20;
      ms[s] = p[16]; ls[s] = p[17];
    }
    float M = fmaxf(fmaxf(fmaxf(ms[0], ms[1]), fmaxf(ms[2], ms[3])),
                    fmaxf(fmaxf(ms[4], ms[5]), fmaxf(ms[6], ms[7])));
    float L = 0.f;
    float4 y0 = {0, 0, 0, 0}, y1 = {0, 0, 0, 0}, y2 = {0, 0, 0, 0},
           y3 = {0, 0, 0, 0};
#pragma unroll
    for (int s = 0; s < 8; s++) {
      float f = __expf(ms[s] - M);
      L = fmaf(f, ls[s], L);
      const float* p = om + (s * 64 + tid) * 20;
      fma4(y0, f, *(const float4*)(p + 0));
      fma4(y1, f, *(const float4*)(p + 4));
      fma4(y2, f, *(const float4*)(p + 8));
      fma4(y3, f, *(const float4*)(p + 12));
    }
    const int qm = masks[b * NT + tq];
    const float inv = (qm != 0 && L > 0.f) ? (1.0f / L) : 0.f;
    y0.x *= inv; y0.y *= inv; y0.z *= inv; y0.w *= inv;
    y1.x *= inv; y1.y *= inv; y1.z *= inv; y1.w *= inv;
    y2.x *= inv; y2.y *= inv; y2.z *= inv; y2.w *= inv;
    y3.x *= inv; y3.y *= inv; y3.z *= inv; y3.w *= inv;
    float4* yo = (float4*)(Y + ((size_t)b * NT + tq) * NE + h * NS);
    yo[0] = y0; yo[1] = y1; yo[2] = y2; yo[3] = y3;
  }
}

// ---------------- Kernel C: out = Y @ Wu^T + bu --------------------------
// grid = B*T/16 = 512 blocks (2 blocks/CU), 256 threads.
// 16 rows/block; threads: c0 = 4 cols, rg = 4 rowgroups x 4 rows, eh = e-half.
// 2-way e-split within block; partials combined via LDS (Wt reused).
__global__ __launch_bounds__(256) void proj_kernel(
    const float* __restrict__ Y, const float* __restrict__ Wu,
    const float* __restrict__ bu, float* __restrict__ out) {
  __shared__ __align__(16) float Wt[64 * WT_PITCH];  // 33792 B
  __shared__ __align__(16) float Yt[16 * 128];       // 8192 B
  const int tid = threadIdx.x;
  const int r0 = blockIdx.x * 16;
  const float4* yg = (const float4*)(Y + (size_t)r0 * 128);
  float4* yt4 = (float4*)Yt;
  yt4[tid] = yg[tid];
  yt4[tid + 256] = yg[tid + 256];
  const int c0 = (tid & 31) << 2;
  const int rg = (tid >> 5) & 3;
  const int eh = tid >> 7;  // 0 or 1
  float4 acc0 = {0, 0, 0, 0}, acc1 = {0, 0, 0, 0}, acc2 = {0, 0, 0, 0},
         acc3 = {0, 0, 0, 0};
  for (int e0 = 0; e0 < 128; e0 += 64) {
    __syncthreads();  // guards Yt staging (iter 0) and Wt reuse (iter 1)
#pragma unroll
    for (int p = 0; p < 8; p++) {
      int idx = tid + p * 256;
      int c = idx >> 4;
      int es = (idx & 15) << 2;
      float4 w = *(const float4*)(Wu + c * 128 + e0 + es);
      Wt[(es + 0) * WT_PITCH + c] = w.x;
      Wt[(es + 1) * WT_PITCH + c] = w.y;
      Wt[(es + 2) * WT_PITCH + c] = w.z;
      Wt[(es + 3) * WT_PITCH + c] = w.w;
    }
    __syncthreads();
    const int eb = eh << 5;  // this thread's e-half within the 64-chunk
    const float* y0 = Yt + (rg * 4 + 0) * 128 + e0 + eb;
    const float* y1 = Yt + (rg * 4 + 1) * 128 + e0 + eb;
    const float* y2 = Yt + (rg * 4 + 2) * 128 + e0 + eb;
    const float* y3 = Yt + (rg * 4 + 3) * 128 + e0 + eb;
#pragma unroll 4
    for (int e = 0; e < 32; e += 4) {
      const float* wb = Wt + (eb + e) * WT_PITCH + c0;
      float4 w0 = *(const float4*)(wb + 0 * WT_PITCH);
      float4 w1 = *(const float4*)(wb + 1 * WT_PITCH);
      float4 w2 = *(const float4*)(wb + 2 * WT_PITCH);
      float4 w3 = *(const float4*)(wb + 3 * WT_PITCH);
      float4 ya = *(const float4*)(y0 + e);
      float4 yb = *(const float4*)(y1 + e);
      float4 yc = *(const float4*)(y2 + e);
      float4 yd = *(const float4*)(y3 + e);
      fma4(acc0, ya.x, w0); fma4(acc0, ya.y, w1); fma4(acc0, ya.z, w2); fma4(acc0, ya.w, w3);
      fma4(acc1, yb.x, w0); fma4(acc1, yb.y, w1); fma4(acc1, yb.z, w2); fma4(acc1, yb.w, w3);
      fma4(acc2, yc.x, w0); fma4(acc2, yc.y, w1); fma4(acc2, yc.z, w2); fma4(acc2, yc.w, w3);
      fma4(acc3, yd.x, w0); fma4(acc3, yd.y, w1); fma4(acc3, yd.z, w2); fma4(acc3, yd.w, w3);
    }
  }
  // combine e-halves through LDS (Wt dead; pitch 20 to spread banks)
  __syncthreads();
  if (eh == 1) {
    float* p = Wt + (tid & 127) * 20;
    *(float4*)(p + 0) = acc0; *(float4*)(p + 4) = acc1;
    *(float4*)(p + 8) = acc2; *(float4*)(p + 12) = acc3;
  }
  __syncthreads();
  if (eh == 0) {
    const float* p = Wt + tid * 20;
    float4 b4 = *(const float4*)(bu + c0);
    float4 q0 = *(const float4*)(p + 0);
    float4 q1 = *(const float4*)(p + 4);
    float4 q2 = *(const float4*)(p + 8);
    float4 q3 = *(const float4*)(p + 12);
    acc0.x += q0.x + b4.x; acc0.y += q0.y + b4.y; acc0.z += q0.z + b4.z; acc0.w += q0.w + b4.w;
    acc1.x += q1.x + b4.x; acc1.y += q1.y + b4.y; acc1.z += q1.z + b4.z; acc1.w += q1.w + b4.w;
    acc2.x += q2.x + b4.x; acc2.y += q2.y + b4.y; acc2.z += q2.z + b4.z; acc2.w += q2.w + b4.w;
    acc3.x += q3.x + b4.x; acc3.y += q3.y + b4.y; acc3.z += q3.z + b4.z; acc3.w += q3.w + b4.w;
    *(float4*)(out + (size_t)(r0 + rg * 4 + 0) * 128 + c0) = acc0;
    *(float4*)(out + (size_t)(r0 + rg * 4 + 1) * 128 + c0) = acc1;
    *(float4*)(out + (size_t)(r0 + rg * 4 + 2) * 128 + c0) = acc2;
    *(float4*)(out + (size_t)(r0 + rg * 4 + 3) * 128 + c0) = acc3;
  }
}

extern "C" void kernel_launch(void* const* d_in, const int* in_sizes, int n_in,
                              void* d_out, int out_size, void* d_ws,
                              size_t ws_size, hipStream_t stream) {
  const float* x = (const float*)d_in[0];
  const int* masks = (const int*)d_in[1];
  const float* Wq = (const float*)d_in[2];
  const float* Wk = (const float*)d_in[3];
  const float* Wv = (const float*)d_in[4];
  const float* Wu = (const float*)d_in[5];
  const float* bu = (const float*)d_in[6];
  float* out = (float*)d_out;

  float* ws = (float*)d_ws;
  float* Q = ws + WS_Q;
  float* K = ws + WS_K;
  float* V = ws + WS_V;
  float* Y = ws + WS_Y;
  int* vidx = (int*)(ws + WS_VIDX);
  int* vcount = vidx + NB * NT;

  qkv_kernel<<<1024 + NB, 256, 0, stream>>>(x, masks, Wq, Wk, Wv, Q, K, V,
                                            vidx, vcount);
  attn_kernel<<<NB * NH * (NT / 128), 512, 0, stream>>>(Q, K, V, masks, vidx,
                                                        vcount, Y);
  proj_kernel<<<NB * NT / 16, 256, 0, stream>>>(Y, Wu, bu, out);
}

// Round 3
// 136.868 us; speedup vs baseline: 1.7820x; 1.0787x over previous
//
#include <hip/hip_runtime.h>

#define NB 8
#define NT 1024
#define NE 128
#define NH 8
#define NS 16

// Workspace layout (floats). Each of Q/K/V/Y is B*H*T*S = B*T*E = 1048576 floats (4 MB).
#define WS_Q 0
#define WS_K 1048576
#define WS_V 2097152
#define WS_Y 3145728
#define WS_VIDX 4194304

#define WT_PITCH 132  // multiple of 4 -> every row 16B-aligned for float4 LDS reads

typedef float v2f __attribute__((ext_vector_type(2)));

static __device__ __forceinline__ v2f vlo(const float4 v) { return v2f{v.x, v.y}; }
static __device__ __forceinline__ v2f vhi(const float4 v) { return v2f{v.z, v.w}; }
static __device__ __forceinline__ v2f pfma(v2f a, v2f b, v2f c) {
  return __builtin_elementwise_fma(a, b, c);  // v_pk_fma_f32 on gfx950
}

static __device__ __forceinline__ void fma4(float4& acc, float s, const float4 v) {
  acc.x = fmaf(s, v.x, acc.x);
  acc.y = fmaf(s, v.y, acc.y);
  acc.z = fmaf(s, v.z, acc.z);
  acc.w = fmaf(s, v.w, acc.w);
}

static __device__ __forceinline__ float dot16(const float4 x0, const float4 x1,
                                              const float4 x2, const float4 x3,
                                              const float4 w0, const float4 w1,
                                              const float4 w2, const float4 w3) {
  float s0 = (x0.x * w0.x + x0.y * w0.y) + (x0.z * w0.z + x0.w * w0.w);
  float s1 = (x1.x * w1.x + x1.y * w1.y) + (x1.z * w1.z + x1.w * w1.w);
  float s2 = (x2.x * w2.x + x2.y * w2.y) + (x2.z * w2.z + x2.w * w2.w);
  float s3 = (x3.x * w3.x + x3.y * w3.y) + (x3.z * w3.z + x3.w * w3.w);
  return (s0 + s1) + (s2 + s3);
}

// Packed-FP32 dot of two 16-float vectors: 8 v_pk_fma/mul + 1 v_pk_add + 1 add
// (~10 VALU vs ~19 scalar). Numerically identical op set (fma).
static __device__ __forceinline__ float dot16p(const float4 q0, const float4 q1,
                                               const float4 q2, const float4 q3,
                                               const float4 k0, const float4 k1,
                                               const float4 k2, const float4 k3) {
  v2f a = vlo(q0) * vlo(k0);
  v2f b = vhi(q0) * vhi(k0);
  a = pfma(vlo(q1), vlo(k1), a);
  b = pfma(vhi(q1), vhi(k1), b);
  a = pfma(vlo(q2), vlo(k2), a);
  b = pfma(vhi(q2), vhi(k2), b);
  a = pfma(vlo(q3), vlo(k3), a);
  b = pfma(vhi(q3), vhi(k3), b);
  v2f c = a + b;
  return c.x + c.y;
}

// ---------------- Kernel A: fused QKV projection + mask compaction -------
// blocks [0,1024): qkv. block -> (h = blk&7, rowgroup = blk>>3 of 64 rows).
// Thread: d = tid&15, rows = base + (tid>>4)*4 .. +3. W rows in registers.
// blocks [1024,1032): per-batch mask compaction (wave 0 only).
__global__ __launch_bounds__(256) void qkv_kernel(
    const float* __restrict__ x, const int* __restrict__ masks,
    const float* __restrict__ Wq, const float* __restrict__ Wk,
    const float* __restrict__ Wv, float* __restrict__ Q, float* __restrict__ K,
    float* __restrict__ V, int* __restrict__ vidx, int* __restrict__ vcount) {
  if (blockIdx.x >= 1024) {
    const int b = blockIdx.x - 1024;
    const int lane = threadIdx.x;
    if (lane < 64) {
      int base = 0;
      for (int c = 0; c < NT; c += 64) {
        int t = c + lane;
        int v = masks[b * NT + t] != 0;
        unsigned long long bal = __ballot(v);
        int pos = base + __popcll(bal & ((1ull << lane) - 1ull));
        if (v) vidx[b * NT + pos] = t;
        base += __popcll(bal);
      }
      if (lane == 0) vcount[b] = base;
    }
    return;
  }
  const int tid = threadIdx.x;
  const int h = blockIdx.x & 7;
  const int rg = blockIdx.x >> 3;  // 0..127
  const int b = rg >> 4;
  const int base = rg << 6;              // global row base (b*NT + t)
  const int d = tid & 15;
  const int r = base + ((tid >> 4) << 2);  // first of this thread's 4 rows
  const float4* wq4 = (const float4*)(Wq + d * 16);
  const float4 wq0 = wq4[0], wq1 = wq4[1], wq2 = wq4[2], wq3 = wq4[3];
  const float4* wk4 = (const float4*)(Wk + d * 16);
  const float4 wk0 = wk4[0], wk1 = wk4[1], wk2 = wk4[2], wk3 = wk4[3];
  const float4* wv4 = (const float4*)(Wv + d * 16);
  const float4 wv0 = wv4[0], wv1 = wv4[1], wv2 = wv4[2], wv3 = wv4[3];
  const float invs = 0.08838834764831845f;  // 1/sqrt(128)
#pragma unroll
  for (int i = 0; i < 4; i++) {
    const int row = r + i;
    const float4* xp = (const float4*)(x + (size_t)row * 128 + h * 16);
    const float4 x0 = xp[0], x1 = xp[1], x2 = xp[2], x3 = xp[3];
    float aq = dot16(x0, x1, x2, x3, wq0, wq1, wq2, wq3);
    float ak = dot16(x0, x1, x2, x3, wk0, wk1, wk2, wk3);
    float av = dot16(x0, x1, x2, x3, wv0, wv1, wv2, wv3);
    const int t = row & 1023;
    size_t o = ((size_t)(b * NH + h) * NT + t) * NS + d;
    Q[o] = aq * invs;
    K[o] = ak;
    V[o] = av;
  }
}

// ---------------- Kernel B: split-K masked attention, 2 queries/thread ---
// Round-0 structure (known 58.8 us): grid = B*H*(T/128) = 512 blocks, 256 thr.
// Block = 128 queries x 4 key-splits. Wave s handles tile rows r == s (mod 4).
// Each thread owns 2 queries (tA = base+lane, tB = tA+64).
// Round-2 post-mortem: VALU busy-time is the invariant (~32 us at both 8 and
// 16 waves/CU) -> the lever is VALU instruction count, not occupancy. This
// version keeps the structure and halves the FMA instruction stream with
// packed FP32 (v_pk_fma_f32 via float2 elementwise fma).
__global__ __launch_bounds__(256) void attn_kernel(
    const float* __restrict__ Q, const float* __restrict__ K,
    const float* __restrict__ V, const int* __restrict__ masks,
    const int* __restrict__ vidx, const int* __restrict__ vcount,
    float* __restrict__ Y) {
  __shared__ __align__(16) float Ks[2048];
  __shared__ __align__(16) float Vs[2048];
  __shared__ __align__(16) float om[2][4][64][20];  // raw o partials, pitch 20
  __shared__ float ml[2][4][64][2];                 // (m,l) per (qg,split,lane)
  const int tid = threadIdx.x;
  const int lane = tid & 63;
  const int split = tid >> 6;  // 0..3
  const int bh = blockIdx.x >> 3;
  const int b = bh >> 3, h = bh & 7;
  const int tbase = (blockIdx.x & 7) << 7;
  const int tA = tbase + lane;
  const int nv = vcount[b];
  const float4* qga = (const float4*)(Q + ((size_t)bh * NT + tA) * NS);
  const float4 qa0 = qga[0], qa1 = qga[1], qa2 = qga[2], qa3 = qga[3];
  const float4* qgb = (const float4*)(Q + ((size_t)bh * NT + tA + 64) * NS);
  const float4 qb0 = qgb[0], qb1 = qgb[1], qb2 = qgb[2], qb3 = qgb[3];
  float mA = -1e30f, lA = 0.f, mB = -1e30f, lB = 0.f;
  v2f oa[8], ob[8];
#pragma unroll
  for (int j = 0; j < 8; j++) { oa[j] = v2f{0.f, 0.f}; ob[j] = v2f{0.f, 0.f}; }

  for (int k0 = 0; k0 < nv; k0 += 128) {
    __syncthreads();
    // stage 128 gathered K/V rows cooperatively (zero-fill past nv)
    const int quad = tid & 3;
    const int jr = tid >> 2;  // 0..63
#pragma unroll
    for (int p = 0; p < 2; p++) {
      int row = jr + (p << 6);
      int j = k0 + row;
      float4 kv = {0, 0, 0, 0}, vv = {0, 0, 0, 0};
      if (j < nv) {
        int kk = vidx[b * NT + j];
        size_t bse = ((size_t)bh * NT + kk) * NS + (quad << 2);
        kv = *(const float4*)(K + bse);
        vv = *(const float4*)(V + bse);
      }
      *(float4*)(Ks + row * 16 + (quad << 2)) = kv;
      *(float4*)(Vs + row * 16 + (quad << 2)) = vv;
    }
    __syncthreads();
    int jmax = nv - k0;
    if (jmax > 128) jmax = 128;
    for (int g = 0; g < 8; g++) {
      const int rbase = split + (g << 4);
      if (rbase >= jmax) break;  // wave-uniform
      float sA[4], sB[4];
#pragma unroll
      for (int i = 0; i < 4; i++) {
        const float4* kr = (const float4*)(Ks + (rbase + (i << 2)) * 16);
        float4 k0v = kr[0], k1v = kr[1], k2v = kr[2], k3v = kr[3];
        sA[i] = dot16p(qa0, qa1, qa2, qa3, k0v, k1v, k2v, k3v);
        sB[i] = dot16p(qb0, qb1, qb2, qb3, k0v, k1v, k2v, k3v);
      }
#pragma unroll
      for (int i = 0; i < 4; i++)
        if (rbase + (i << 2) >= jmax) { sA[i] = -1e30f; sB[i] = -1e30f; }
      // online update, query A
      float mbA = fmaxf(fmaxf(sA[0], sA[1]), fmaxf(sA[2], sA[3]));
      if (mbA > mA) {
        float al = __expf(mA - mbA);
        v2f al2 = {al, al};
        lA *= al;
#pragma unroll
        for (int j = 0; j < 8; j++) oa[j] *= al2;
        mA = mbA;
      }
      float pA[4];
      pA[0] = __expf(sA[0] - mA); pA[1] = __expf(sA[1] - mA);
      pA[2] = __expf(sA[2] - mA); pA[3] = __expf(sA[3] - mA);
      lA += (pA[0] + pA[1]) + (pA[2] + pA[3]);
      // online update, query B
      float mbB = fmaxf(fmaxf(sB[0], sB[1]), fmaxf(sB[2], sB[3]));
      if (mbB > mB) {
        float al = __expf(mB - mbB);
        v2f al2 = {al, al};
        lB *= al;
#pragma unroll
        for (int j = 0; j < 8; j++) ob[j] *= al2;
        mB = mbB;
      }
      float pB[4];
      pB[0] = __expf(sB[0] - mB); pB[1] = __expf(sB[1] - mB);
      pB[2] = __expf(sB[2] - mB); pB[3] = __expf(sB[3] - mB);
      lB += (pB[0] + pB[1]) + (pB[2] + pB[3]);
#pragma unroll
      for (int i = 0; i < 4; i++) {
        const float4* vr = (const float4*)(Vs + (rbase + (i << 2)) * 16);
        float4 v0 = vr[0], v1 = vr[1], v2 = vr[2], v3 = vr[3];
        const v2f pa2 = {pA[i], pA[i]};
        const v2f pb2 = {pB[i], pB[i]};
        oa[0] = pfma(pa2, vlo(v0), oa[0]); oa[1] = pfma(pa2, vhi(v0), oa[1]);
        oa[2] = pfma(pa2, vlo(v1), oa[2]); oa[3] = pfma(pa2, vhi(v1), oa[3]);
        oa[4] = pfma(pa2, vlo(v2), oa[4]); oa[5] = pfma(pa2, vhi(v2), oa[5]);
        oa[6] = pfma(pa2, vlo(v3), oa[6]); oa[7] = pfma(pa2, vhi(v3), oa[7]);
        ob[0] = pfma(pb2, vlo(v0), ob[0]); ob[1] = pfma(pb2, vhi(v0), ob[1]);
        ob[2] = pfma(pb2, vlo(v1), ob[2]); ob[3] = pfma(pb2, vhi(v1), ob[3]);
        ob[4] = pfma(pb2, vlo(v2), ob[4]); ob[5] = pfma(pb2, vhi(v2), ob[5]);
        ob[6] = pfma(pb2, vlo(v3), ob[6]); ob[7] = pfma(pb2, vhi(v3), ob[7]);
      }
    }
  }
  // ---- write raw partials; one sync; waves 0/1 combine ----
  ml[0][split][lane][0] = mA; ml[0][split][lane][1] = lA;
  ml[1][split][lane][0] = mB; ml[1][split][lane][1] = lB;
  {
    float* pa = &om[0][split][lane][0];
#pragma unroll
    for (int j = 0; j < 8; j++) *(v2f*)(pa + j * 2) = oa[j];
    float* pb = &om[1][split][lane][0];
#pragma unroll
    for (int j = 0; j < 8; j++) *(v2f*)(pb + j * 2) = ob[j];
  }
  __syncthreads();
  if (split < 2) {
    const int qg = split;
    const int tq = tbase + (qg << 6) + lane;
    float m0 = ml[qg][0][lane][0], l0 = ml[qg][0][lane][1];
    float m1 = ml[qg][1][lane][0], l1 = ml[qg][1][lane][1];
    float m2 = ml[qg][2][lane][0], l2 = ml[qg][2][lane][1];
    float m3 = ml[qg][3][lane][0], l3 = ml[qg][3][lane][1];
    float M = fmaxf(fmaxf(m0, m1), fmaxf(m2, m3));
    float f0 = __expf(m0 - M), f1 = __expf(m1 - M), f2 = __expf(m2 - M),
          f3 = __expf(m3 - M);
    float L = f0 * l0 + f1 * l1 + f2 * l2 + f3 * l3;
    float4 y0 = {0, 0, 0, 0}, y1 = {0, 0, 0, 0}, y2 = {0, 0, 0, 0},
           y3 = {0, 0, 0, 0};
    float fs[4] = {f0, f1, f2, f3};
#pragma unroll
    for (int s = 0; s < 4; s++) {
      const float* p = &om[qg][s][lane][0];
      fma4(y0, fs[s], *(const float4*)(p + 0));
      fma4(y1, fs[s], *(const float4*)(p + 4));
      fma4(y2, fs[s], *(const float4*)(p + 8));
      fma4(y3, fs[s], *(const float4*)(p + 12));
    }
    const int qm = masks[b * NT + tq];
    const float inv = (qm != 0 && L > 0.f) ? (1.0f / L) : 0.f;
    y0.x *= inv; y0.y *= inv; y0.z *= inv; y0.w *= inv;
    y1.x *= inv; y1.y *= inv; y1.z *= inv; y1.w *= inv;
    y2.x *= inv; y2.y *= inv; y2.z *= inv; y2.w *= inv;
    y3.x *= inv; y3.y *= inv; y3.z *= inv; y3.w *= inv;
    float4* yo = (float4*)(Y + ((size_t)b * NT + tq) * NE + h * NS);
    yo[0] = y0; yo[1] = y1; yo[2] = y2; yo[3] = y3;
  }
}

// ---------------- Kernel C: out = Y @ Wu^T + bu --------------------------
// grid = B*T/16 = 512 blocks (2 blocks/CU), 256 threads.
// 16 rows/block; threads: c0 = 4 cols, rg = 4 rowgroups x 4 rows, eh = e-half.
// 2-way e-split within block; partials combined via LDS (Wt reused).
__global__ __launch_bounds__(256) void proj_kernel(
    const float* __restrict__ Y, const float* __restrict__ Wu,
    const float* __restrict__ bu, float* __restrict__ out) {
  __shared__ __align__(16) float Wt[64 * WT_PITCH];  // 33792 B
  __shared__ __align__(16) float Yt[16 * 128];       // 8192 B
  const int tid = threadIdx.x;
  const int r0 = blockIdx.x * 16;
  const float4* yg = (const float4*)(Y + (size_t)r0 * 128);
  float4* yt4 = (float4*)Yt;
  yt4[tid] = yg[tid];
  yt4[tid + 256] = yg[tid + 256];
  const int c0 = (tid & 31) << 2;
  const int rg = (tid >> 5) & 3;
  const int eh = tid >> 7;  // 0 or 1
  float4 acc0 = {0, 0, 0, 0}, acc1 = {0, 0, 0, 0}, acc2 = {0, 0, 0, 0},
         acc3 = {0, 0, 0, 0};
  for (int e0 = 0; e0 < 128; e0 += 64) {
    __syncthreads();  // guards Yt staging (iter 0) and Wt reuse (iter 1)
#pragma unroll
    for (int p = 0; p < 8; p++) {
      int idx = tid + p * 256;
      int c = idx >> 4;
      int es = (idx & 15) << 2;
      float4 w = *(const float4*)(Wu + c * 128 + e0 + es);
      Wt[(es + 0) * WT_PITCH + c] = w.x;
      Wt[(es + 1) * WT_PITCH + c] = w.y;
      Wt[(es + 2) * WT_PITCH + c] = w.z;
      Wt[(es + 3) * WT_PITCH + c] = w.w;
    }
    __syncthreads();
    const int eb = eh << 5;  // this thread's e-half within the 64-chunk
    const float* y0 = Yt + (rg * 4 + 0) * 128 + e0 + eb;
    const float* y1 = Yt + (rg * 4 + 1) * 128 + e0 + eb;
    const float* y2 = Yt + (rg * 4 + 2) * 128 + e0 + eb;
    const float* y3 = Yt + (rg * 4 + 3) * 128 + e0 + eb;
#pragma unroll 4
    for (int e = 0; e < 32; e += 4) {
      const float* wb = Wt + (eb + e) * WT_PITCH + c0;
      float4 w0 = *(const float4*)(wb + 0 * WT_PITCH);
      float4 w1 = *(const float4*)(wb + 1 * WT_PITCH);
      float4 w2 = *(const float4*)(wb + 2 * WT_PITCH);
      float4 w3 = *(const float4*)(wb + 3 * WT_PITCH);
      float4 ya = *(const float4*)(y0 + e);
      float4 yb = *(const float4*)(y1 + e);
      float4 yc = *(const float4*)(y2 + e);
      float4 yd = *(const float4*)(y3 + e);
      fma4(acc0, ya.x, w0); fma4(acc0, ya.y, w1); fma4(acc0, ya.z, w2); fma4(acc0, ya.w, w3);
      fma4(acc1, yb.x, w0); fma4(acc1, yb.y, w1); fma4(acc1, yb.z, w2); fma4(acc1, yb.w, w3);
      fma4(acc2, yc.x, w0); fma4(acc2, yc.y, w1); fma4(acc2, yc.z, w2); fma4(acc2, yc.w, w3);
      fma4(acc3, yd.x, w0); fma4(acc3, yd.y, w1); fma4(acc3, yd.z, w2); fma4(acc3, yd.w, w3);
    }
  }
  // combine e-halves through LDS (Wt dead; pitch 20 to spread banks)
  __syncthreads();
  if (eh == 1) {
    float* p = Wt + (tid & 127) * 20;
    *(float4*)(p + 0) = acc0; *(float4*)(p + 4) = acc1;
    *(float4*)(p + 8) = acc2; *(float4*)(p + 12) = acc3;
  }
  __syncthreads();
  if (eh == 0) {
    const float* p = Wt + tid * 20;
    float4 b4 = *(const float4*)(bu + c0);
    float4 q0 = *(const float4*)(p + 0);
    float4 q1 = *(const float4*)(p + 4);
    float4 q2 = *(const float4*)(p + 8);
    float4 q3 = *(const float4*)(p + 12);
    acc0.x += q0.x + b4.x; acc0.y += q0.y + b4.y; acc0.z += q0.z + b4.z; acc0.w += q0.w + b4.w;
    acc1.x += q1.x + b4.x; acc1.y += q1.y + b4.y; acc1.z += q1.z + b4.z; acc1.w += q1.w + b4.w;
    acc2.x += q2.x + b4.x; acc2.y += q2.y + b4.y; acc2.z += q2.z + b4.z; acc2.w += q2.w + b4.w;
    acc3.x += q3.x + b4.x; acc3.y += q3.y + b4.y; acc3.z += q3.z + b4.z; acc3.w += q3.w + b4.w;
    *(float4*)(out + (size_t)(r0 + rg * 4 + 0) * 128 + c0) = acc0;
    *(float4*)(out + (size_t)(r0 + rg * 4 + 1) * 128 + c0) = acc1;
    *(float4*)(out + (size_t)(r0 + rg * 4 + 2) * 128 + c0) = acc2;
    *(float4*)(out + (size_t)(r0 + rg * 4 + 3) * 128 + c0) = acc3;
  }
}

extern "C" void kernel_launch(void* const* d_in, const int* in_sizes, int n_in,
                              void* d_out, int out_size, void* d_ws,
                              size_t ws_size, hipStream_t stream) {
  const float* x = (const float*)d_in[0];
  const int* masks = (const int*)d_in[1];
  const float* Wq = (const float*)d_in[2];
  const float* Wk = (const float*)d_in[3];
  const float* Wv = (const float*)d_in[4];
  const float* Wu = (const float*)d_in[5];
  const float* bu = (const float*)d_in[6];
  float* out = (float*)d_out;

  float* ws = (float*)d_ws;
  float* Q = ws + WS_Q;
  float* K = ws + WS_K;
  float* V = ws + WS_V;
  float* Y = ws + WS_Y;
  int* vidx = (int*)(ws + WS_VIDX);
  int* vcount = vidx + NB * NT;

  qkv_kernel<<<1024 + NB, 256, 0, stream>>>(x, masks, Wq, Wk, Wv, Q, K, V,
                                            vidx, vcount);
  attn_kernel<<<NB * NH * (NT / 128), 256, 0, stream>>>(Q, K, V, masks, vidx,
                                                        vcount, Y);
  proj_kernel<<<NB * NT / 16, 256, 0, stream>>>(Y, Wu, bu, out);
}